// Round 6
// baseline (35.928 us; speedup 1.0000x reference)
//
#include <hip/hip_runtime.h>

// Head: fused GEMM (M=204800, K=128, N=84->96 padded) + DFL softmax + box decode + sigmoid.
// R6: pipelined persistent waves. 512 blocks x 4 waves; each wave processes 3-4
// 32-row tiles (grid-stride 2048) with register double-buffered x (A/B), so 16
// dwordx4 stay in flight while MFMA+epilogue run on the other buffer. Weights
// staged to LDS ONCE per block (amortized), barrier once.

typedef _Float16 half8 __attribute__((ext_vector_type(8)));
typedef float f32x4v __attribute__((ext_vector_type(4)));

constexpr int Ww = 80;
constexpr int HW = 6400;
constexpr int Cc = 128;
constexpr int NPAD = 96;             // 6 N-tiles of 16: 64 box + 20 cls + 12 pad
constexpr int WT_STRIDE = 136;       // f16 elems; 272B row -> 2-way bank alias (free)
constexpr int NTILES = 6400;         // 32-row tiles
constexpr int NWAVES = 2048;         // 512 blocks * 4 waves

__device__ __forceinline__ float sigm(float v) {
    return __builtin_amdgcn_rcpf(1.f + __expf(-v));
}

__global__ __launch_bounds__(256, 2)
void head_kernel(const float* __restrict__ x,
                 const float* __restrict__ w_box,
                 const float* __restrict__ b_box,
                 const float* __restrict__ w_cls,
                 const float* __restrict__ b_cls,
                 const int*   __restrict__ stride_p,
                 float* __restrict__ out)
{
    __shared__ __align__(16) _Float16 Wt[NPAD][WT_STRIDE]; // Wt[ch][k]
    __shared__ __align__(16) float bias_s[NPAD];

    const int tid  = threadIdx.x;
    const int wave = tid >> 6;
    const int lane = tid & 63;
    const int c    = lane & 15;     // A channel-in-tile / B spatial-row / D col
    const int g    = lane >> 4;     // quarter-group; D row = 4g + reg

    // ---- stage Wt[ch][k] = w[k][ch] (f16) once per block ----
    for (int i = tid; i < 128 * 16; i += 256) {
        int k  = i >> 4;
        int c4 = (i & 15) << 2;
        f32x4v v = *(const f32x4v*)&w_box[k * 64 + c4];
        Wt[c4 + 0][k] = (_Float16)v[0];
        Wt[c4 + 1][k] = (_Float16)v[1];
        Wt[c4 + 2][k] = (_Float16)v[2];
        Wt[c4 + 3][k] = (_Float16)v[3];
    }
    for (int i = tid; i < 128 * 5; i += 256) {
        int k  = i / 5;
        int c4 = (i - k * 5) << 2;
        f32x4v v = *(const f32x4v*)&w_cls[k * 20 + c4];
        Wt[64 + c4 + 0][k] = (_Float16)v[0];
        Wt[64 + c4 + 1][k] = (_Float16)v[1];
        Wt[64 + c4 + 2][k] = (_Float16)v[2];
        Wt[64 + c4 + 3][k] = (_Float16)v[3];
    }
    for (int i = tid; i < 12 * 128; i += 256) {
        int ch = 84 + (i >> 7);
        int k  = i & 127;
        Wt[ch][k] = (_Float16)0.f;
    }
    if (tid < NPAD) {
        float bv = 0.f;
        if (tid < 64)      bv = b_box[tid];
        else if (tid < 84) bv = b_cls[tid - 64];
        bias_s[tid] = bv;
    }
    __syncthreads();

    const float sf = (float)stride_p[0];
    f32x4v bl[6];
    #pragma unroll
    for (int nt = 0; nt < 6; ++nt)
        bl[nt] = *(const f32x4v*)&bias_s[nt * 16 + g * 4];

    const int wid = blockIdx.x * 4 + wave;   // 0..2047
    const int t0 = wid, t1 = wid + NWAVES, t2 = wid + 2 * NWAVES, t3 = wid + 3 * NWAVES;
    const bool has4 = (t3 < NTILES);         // t0..t2 always valid

    f32x4v xvA[4][2][2], xvB[4][2][2];

    auto load_tile = [&](f32x4v (&xv)[4][2][2], int tile) {
        const float* xb = x + (size_t)(tile * 32 + c) * Cc + g * 8;
        #pragma unroll
        for (int ks = 0; ks < 4; ++ks)
            #pragma unroll
            for (int rt = 0; rt < 2; ++rt) {
                const float* p = xb + rt * 16 * Cc + ks * 32;
                xv[ks][rt][0] = *(const f32x4v*)p;
                xv[ks][rt][1] = *(const f32x4v*)(p + 4);
            }
        __builtin_amdgcn_sched_barrier(0);   // pin load issue here
    };

    auto compute_tile = [&](f32x4v (&xv)[4][2][2], int tile) {
        f32x4v acc[2][6];
        #pragma unroll
        for (int i = 0; i < 2; ++i)
            #pragma unroll
            for (int j = 0; j < 6; ++j)
                acc[i][j] = (f32x4v){0.f, 0.f, 0.f, 0.f};

        #pragma unroll
        for (int ks = 0; ks < 4; ++ks) {
            half8 wfrag[6];
            #pragma unroll
            for (int nt = 0; nt < 6; ++nt)
                wfrag[nt] = *(const half8*)&Wt[nt * 16 + c][ks * 32 + g * 8];
            #pragma unroll
            for (int rt = 0; rt < 2; ++rt) {
                f32x4v lo = xv[ks][rt][0], hi = xv[ks][rt][1];
                half8 b;
                b[0] = (_Float16)lo[0]; b[1] = (_Float16)lo[1];
                b[2] = (_Float16)lo[2]; b[3] = (_Float16)lo[3];
                b[4] = (_Float16)hi[0]; b[5] = (_Float16)hi[1];
                b[6] = (_Float16)hi[2]; b[7] = (_Float16)hi[3];
                #pragma unroll
                for (int nt = 0; nt < 6; ++nt)
                    acc[rt][nt] = __builtin_amdgcn_mfma_f32_16x16x32_f16(wfrag[nt], b, acc[rt][nt], 0, 0, 0);
            }
        }

        const int mb = tile * 32;
        #pragma unroll
        for (int rt = 0; rt < 2; ++rt) {
            const int m   = mb + rt * 16 + c;
            const int pos = m % HW;
            const int yp  = pos / Ww;
            const int xq  = pos - yp * Ww;
            const float ax = ((float)xq + 0.5f) * sf;
            const float ay = ((float)yp + 0.5f) * sf;

            float dfl[4];
            #pragma unroll
            for (int t = 0; t < 4; ++t) {
                f32x4v v = acc[rt][t] + bl[t];
                float e0 = __expf(v[0]), e1 = __expf(v[1]);
                float e2 = __expf(v[2]), e3 = __expf(v[3]);
                float s  = e0 + e1 + e2 + e3;
                float ws = e1 + 2.f * e2 + 3.f * e3 + (float)(4 * g) * s;
                s  += __shfl_xor(s, 16, 64);
                s  += __shfl_xor(s, 32, 64);
                ws += __shfl_xor(ws, 16, 64);
                ws += __shfl_xor(ws, 32, 64);
                dfl[t] = ws * __builtin_amdgcn_rcpf(s);
            }
            const float w2 = dfl[2] - dfl[0], w3 = dfl[3] - dfl[1];

            float* op = out + (size_t)m * 24;

            f32x4v vA = acc[rt][4] + bl[4];
            f32x4v clsA;
            clsA[0] = sigm(vA[0]); clsA[1] = sigm(vA[1]);
            clsA[2] = sigm(vA[2]); clsA[3] = sigm(vA[3]);
            *(f32x4v*)(op + 4 + 4 * g) = clsA;

            if (g == 0) {
                f32x4v box = { ax + 0.5f * w2, ay + 0.5f * w3, w2, w3 };
                *(f32x4v*)op = box;
                f32x4v vB = acc[rt][5] + bl[5];
                f32x4v clsB;
                clsB[0] = sigm(vB[0]); clsB[1] = sigm(vB[1]);
                clsB[2] = sigm(vB[2]); clsB[3] = sigm(vB[3]);
                *(f32x4v*)(op + 20) = clsB;
            }
        }
    };

    // ---- pipelined schedule: 16 loads always in flight ----
    load_tile(xvA, t0);
    load_tile(xvB, t1);
    compute_tile(xvA, t0);
    load_tile(xvA, t2);
    compute_tile(xvB, t1);
    if (has4) load_tile(xvB, t3);
    compute_tile(xvA, t2);
    if (has4) compute_tile(xvB, t3);
}

extern "C" void kernel_launch(void* const* d_in, const int* in_sizes, int n_in,
                              void* d_out, int out_size, void* d_ws, size_t ws_size,
                              hipStream_t stream) {
    const float* x      = (const float*)d_in[0];
    const float* w_box  = (const float*)d_in[1];
    const float* b_box  = (const float*)d_in[2];
    const float* w_cls  = (const float*)d_in[3];
    const float* b_cls  = (const float*)d_in[4];
    const int*   stride_p = (const int*)d_in[5];
    float* out = (float*)d_out;

    dim3 grid(512), block(256);
    hipLaunchKernelGGL(head_kernel, grid, block, 0, stream,
                       x, w_box, b_box, w_cls, b_cls, stride_p, out);
}

// Round 8
// 32.833 us; speedup vs baseline: 1.0943x; 1.0943x over previous
//
#include <hip/hip_runtime.h>

// Head: fused GEMM (M=204800, K=128, N=84->96 padded) + DFL softmax + box decode + sigmoid.
// R8 = R7 with the cvt_pkrtz type fixed (__fp16 vector overlay in the union).
//   - exp via __builtin_amdgcn_exp2f (1 instr), sigmoid = rcp(1+exp2(-1.4427v))
//   - f16 pack via v_cvt_pkrtz
//   - wave-uniform anchor math, no per-lane div/mod
//   - epilogue stores transposed through per-wave LDS -> dense dwordx4 global stores

typedef _Float16 half8 __attribute__((ext_vector_type(8)));
typedef __fp16  fp16x2 __attribute__((ext_vector_type(2)));
typedef float f32x4v __attribute__((ext_vector_type(4)));

constexpr int Ww = 80;
constexpr int Cc = 128;
constexpr int NPAD = 96;             // 6 N-tiles of 16: 64 box + 20 cls + 12 pad
constexpr int WT_STRIDE = 136;       // f16 elems; 272B row -> 2-way bank alias (free)
constexpr int NTILES = 6400;         // 32-row tiles (200 tiles per image, exact)
constexpr int NWAVES = 2048;         // 512 blocks * 4 waves
constexpr float LOG2E = 1.44269504088896f;

union H8 { half8 h; fp16x2 p[4]; };

__device__ __forceinline__ float sigm(float v) {
    return __builtin_amdgcn_rcpf(1.f + __builtin_amdgcn_exp2f(-LOG2E * v));
}

__global__ __launch_bounds__(256, 2)
void head_kernel(const float* __restrict__ x,
                 const float* __restrict__ w_box,
                 const float* __restrict__ b_box,
                 const float* __restrict__ w_cls,
                 const float* __restrict__ b_cls,
                 const int*   __restrict__ stride_p,
                 float* __restrict__ out)
{
    __shared__ __align__(16) _Float16 Wt[NPAD][WT_STRIDE]; // Wt[ch][k]
    __shared__ __align__(16) float bias_s[NPAD];
    __shared__ __align__(16) float sc[4][32][24];          // per-wave store-transpose scratch

    const int tid  = threadIdx.x;
    const int wave = tid >> 6;
    const int lane = tid & 63;
    const int c    = lane & 15;     // A channel-in-tile / B spatial-row / D col
    const int g    = lane >> 4;     // quarter-group; D row = 4g + reg

    // ---- stage Wt[ch][k] = w[k][ch] (f16) once per block ----
    for (int i = tid; i < 128 * 16; i += 256) {
        int k  = i >> 4;
        int c4 = (i & 15) << 2;
        f32x4v v = *(const f32x4v*)&w_box[k * 64 + c4];
        Wt[c4 + 0][k] = (_Float16)v[0];
        Wt[c4 + 1][k] = (_Float16)v[1];
        Wt[c4 + 2][k] = (_Float16)v[2];
        Wt[c4 + 3][k] = (_Float16)v[3];
    }
    for (int i = tid; i < 128 * 5; i += 256) {
        int k  = i / 5;
        int c4 = (i - k * 5) << 2;
        f32x4v v = *(const f32x4v*)&w_cls[k * 20 + c4];
        Wt[64 + c4 + 0][k] = (_Float16)v[0];
        Wt[64 + c4 + 1][k] = (_Float16)v[1];
        Wt[64 + c4 + 2][k] = (_Float16)v[2];
        Wt[64 + c4 + 3][k] = (_Float16)v[3];
    }
    for (int i = tid; i < 12 * 128; i += 256) {
        int ch = 84 + (i >> 7);
        int k  = i & 127;
        Wt[ch][k] = (_Float16)0.f;
    }
    if (tid < NPAD) {
        float bv = 0.f;
        if (tid < 64)      bv = b_box[tid];
        else if (tid < 84) bv = b_cls[tid - 64];
        bias_s[tid] = bv;
    }
    __syncthreads();

    const float sf = (float)stride_p[0];
    f32x4v bl[6];
    #pragma unroll
    for (int nt = 0; nt < 6; ++nt)
        bl[nt] = *(const f32x4v*)&bias_s[nt * 16 + g * 4];

    const int wid = blockIdx.x * 4 + wave;   // 0..2047
    const int t0 = wid, t1 = wid + NWAVES, t2 = wid + 2 * NWAVES, t3 = wid + 3 * NWAVES;
    const bool has4 = (t3 < NTILES);

    f32x4v xvA[4][2][2], xvB[4][2][2];

    auto load_tile = [&](f32x4v (&xv)[4][2][2], int tile) {
        const float* xb = x + (size_t)(tile * 32 + c) * Cc + g * 8;
        #pragma unroll
        for (int ks = 0; ks < 4; ++ks)
            #pragma unroll
            for (int rt = 0; rt < 2; ++rt) {
                const float* p = xb + rt * 16 * Cc + ks * 32;
                xv[ks][rt][0] = *(const f32x4v*)p;
                xv[ks][rt][1] = *(const f32x4v*)(p + 4);
            }
        __builtin_amdgcn_sched_barrier(0);   // pin load issue here
    };

    auto compute_tile = [&](f32x4v (&xv)[4][2][2], int tile) {
        f32x4v acc[2][6];
        #pragma unroll
        for (int i = 0; i < 2; ++i)
            #pragma unroll
            for (int j = 0; j < 6; ++j)
                acc[i][j] = (f32x4v){0.f, 0.f, 0.f, 0.f};

        #pragma unroll
        for (int ks = 0; ks < 4; ++ks) {
            half8 wfrag[6];
            #pragma unroll
            for (int nt = 0; nt < 6; ++nt)
                wfrag[nt] = *(const half8*)&Wt[nt * 16 + c][ks * 32 + g * 8];
            #pragma unroll
            for (int rt = 0; rt < 2; ++rt) {
                f32x4v lo = xv[ks][rt][0], hi = xv[ks][rt][1];
                H8 bu;
                bu.p[0] = __builtin_amdgcn_cvt_pkrtz(lo[0], lo[1]);
                bu.p[1] = __builtin_amdgcn_cvt_pkrtz(lo[2], lo[3]);
                bu.p[2] = __builtin_amdgcn_cvt_pkrtz(hi[0], hi[1]);
                bu.p[3] = __builtin_amdgcn_cvt_pkrtz(hi[2], hi[3]);
                #pragma unroll
                for (int nt = 0; nt < 6; ++nt)
                    acc[rt][nt] = __builtin_amdgcn_mfma_f32_16x16x32_f16(wfrag[nt], bu.h, acc[rt][nt], 0, 0, 0);
            }
        }

        // anchors: tiles never cross an image (200 tiles/img) or a grid row (80|16)
        const int pos0 = (tile % 200) * 32;            // wave-uniform
        #pragma unroll
        for (int rt = 0; rt < 2; ++rt) {
            const int prow = pos0 + rt * 16;           // uniform
            const int yp   = prow / Ww;                // uniform
            const int xq0  = prow - yp * Ww;           // uniform
            const float ax = ((float)(xq0 + c) + 0.5f) * sf;
            const float ay = ((float)yp + 0.5f) * sf;

            float dfl[4];
            #pragma unroll
            for (int t = 0; t < 4; ++t) {
                f32x4v v = acc[rt][t] + bl[t];
                float e0 = __builtin_amdgcn_exp2f(LOG2E * v[0]);
                float e1 = __builtin_amdgcn_exp2f(LOG2E * v[1]);
                float e2 = __builtin_amdgcn_exp2f(LOG2E * v[2]);
                float e3 = __builtin_amdgcn_exp2f(LOG2E * v[3]);
                float s  = e0 + e1 + e2 + e3;
                float ws = e1 + 2.f * e2 + 3.f * e3 + (float)(4 * g) * s;
                s  += __shfl_xor(s, 16, 64);
                s  += __shfl_xor(s, 32, 64);
                ws += __shfl_xor(ws, 16, 64);
                ws += __shfl_xor(ws, 32, 64);
                dfl[t] = ws * __builtin_amdgcn_rcpf(s);
            }
            const float w2 = dfl[2] - dfl[0], w3 = dfl[3] - dfl[1];

            // stage this row's outputs into per-wave LDS scratch
            float* row = sc[wave][rt * 16 + c];
            f32x4v vA = acc[rt][4] + bl[4];
            f32x4v clsA = { sigm(vA[0]), sigm(vA[1]), sigm(vA[2]), sigm(vA[3]) };
            *(f32x4v*)(row + 4 + 4 * g) = clsA;
            if (g == 0) {
                f32x4v box = { ax + 0.5f * w2, ay + 0.5f * w3, w2, w3 };
                *(f32x4v*)row = box;
                f32x4v vB = acc[rt][5] + bl[5];
                f32x4v clsB = { sigm(vB[0]), sigm(vB[1]), sigm(vB[2]), sigm(vB[3]) };
                *(f32x4v*)(row + 20) = clsB;
            }
        }

        // dense write-out: 32 rows x 24 floats = 192 float4s, 3 per lane
        const float* s0 = &sc[wave][0][0];
        float* orow = out + (size_t)tile * 32 * 24;
        #pragma unroll
        for (int i = 0; i < 3; ++i) {
            f32x4v v = *(const f32x4v*)(s0 + (lane + 64 * i) * 4);
            *(f32x4v*)(orow + (lane + 64 * i) * 4) = v;
        }
    };

    // ---- pipelined schedule: 16 loads always in flight ----
    load_tile(xvA, t0);
    load_tile(xvB, t1);
    compute_tile(xvA, t0);
    load_tile(xvA, t2);
    compute_tile(xvB, t1);
    if (has4) load_tile(xvB, t3);
    compute_tile(xvA, t2);
    if (has4) compute_tile(xvB, t3);
}

extern "C" void kernel_launch(void* const* d_in, const int* in_sizes, int n_in,
                              void* d_out, int out_size, void* d_ws, size_t ws_size,
                              hipStream_t stream) {
    const float* x      = (const float*)d_in[0];
    const float* w_box  = (const float*)d_in[1];
    const float* b_box  = (const float*)d_in[2];
    const float* w_cls  = (const float*)d_in[3];
    const float* b_cls  = (const float*)d_in[4];
    const int*   stride_p = (const int*)d_in[5];
    float* out = (float*)d_out;

    dim3 grid(512), block(256);
    hipLaunchKernelGGL(head_kernel, grid, block, 0, stream,
                       x, w_box, b_box, w_cls, b_cls, stride_p, out);
}

// Round 9
// 31.924 us; speedup vs baseline: 1.1254x; 1.0285x over previous
//
#include <hip/hip_runtime.h>

// Head: fused GEMM (M=204800, K=128, N=84->96 padded) + DFL softmax + box decode + sigmoid.
// R9 = R8 + perfect CU balance: the 256 "extra" (4th) tiles are spread one per
// 8 waves (one per CU) instead of all landing on blocks 0-63. Every CU now
// processes exactly 25 tiles (was 24-vs-32 -> 1.28x tail).

typedef _Float16 half8 __attribute__((ext_vector_type(8)));
typedef __fp16  fp16x2 __attribute__((ext_vector_type(2)));
typedef float f32x4v __attribute__((ext_vector_type(4)));

constexpr int Ww = 80;
constexpr int Cc = 128;
constexpr int NPAD = 96;             // 6 N-tiles of 16: 64 box + 20 cls + 12 pad
constexpr int WT_STRIDE = 136;       // f16 elems; 272B row -> 2-way bank alias (free)
constexpr int NTILES = 6400;         // 32-row tiles (200 tiles per image, exact)
constexpr int NWAVES = 2048;         // 512 blocks * 4 waves
constexpr float LOG2E = 1.44269504088896f;

union H8 { half8 h; fp16x2 p[4]; };

__device__ __forceinline__ float sigm(float v) {
    return __builtin_amdgcn_rcpf(1.f + __builtin_amdgcn_exp2f(-LOG2E * v));
}

__global__ __launch_bounds__(256, 2)
void head_kernel(const float* __restrict__ x,
                 const float* __restrict__ w_box,
                 const float* __restrict__ b_box,
                 const float* __restrict__ w_cls,
                 const float* __restrict__ b_cls,
                 const int*   __restrict__ stride_p,
                 float* __restrict__ out)
{
    __shared__ __align__(16) _Float16 Wt[NPAD][WT_STRIDE]; // Wt[ch][k]
    __shared__ __align__(16) float bias_s[NPAD];
    __shared__ __align__(16) float sc[4][32][24];          // per-wave store-transpose scratch

    const int tid  = threadIdx.x;
    const int wave = tid >> 6;
    const int lane = tid & 63;
    const int c    = lane & 15;     // A channel-in-tile / B spatial-row / D col
    const int g    = lane >> 4;     // quarter-group; D row = 4g + reg

    // ---- stage Wt[ch][k] = w[k][ch] (f16) once per block ----
    for (int i = tid; i < 128 * 16; i += 256) {
        int k  = i >> 4;
        int c4 = (i & 15) << 2;
        f32x4v v = *(const f32x4v*)&w_box[k * 64 + c4];
        Wt[c4 + 0][k] = (_Float16)v[0];
        Wt[c4 + 1][k] = (_Float16)v[1];
        Wt[c4 + 2][k] = (_Float16)v[2];
        Wt[c4 + 3][k] = (_Float16)v[3];
    }
    for (int i = tid; i < 128 * 5; i += 256) {
        int k  = i / 5;
        int c4 = (i - k * 5) << 2;
        f32x4v v = *(const f32x4v*)&w_cls[k * 20 + c4];
        Wt[64 + c4 + 0][k] = (_Float16)v[0];
        Wt[64 + c4 + 1][k] = (_Float16)v[1];
        Wt[64 + c4 + 2][k] = (_Float16)v[2];
        Wt[64 + c4 + 3][k] = (_Float16)v[3];
    }
    for (int i = tid; i < 12 * 128; i += 256) {
        int ch = 84 + (i >> 7);
        int k  = i & 127;
        Wt[ch][k] = (_Float16)0.f;
    }
    if (tid < NPAD) {
        float bv = 0.f;
        if (tid < 64)      bv = b_box[tid];
        else if (tid < 84) bv = b_cls[tid - 64];
        bias_s[tid] = bv;
    }
    __syncthreads();

    const float sf = (float)stride_p[0];
    f32x4v bl[6];
    #pragma unroll
    for (int nt = 0; nt < 6; ++nt)
        bl[nt] = *(const f32x4v*)&bias_s[nt * 16 + g * 4];

    const int wid = blockIdx.x * 4 + wave;   // 0..2047
    const int t0 = wid, t1 = wid + NWAVES, t2 = wid + 2 * NWAVES;
    const bool has4 = (wid & 7) == 0;        // one 4th-tile wave per CU
    const int t3 = 3 * NWAVES + (wid >> 3);  // [6144, 6400)

    f32x4v xvA[4][2][2], xvB[4][2][2];

    auto load_tile = [&](f32x4v (&xv)[4][2][2], int tile) {
        const float* xb = x + (size_t)(tile * 32 + c) * Cc + g * 8;
        #pragma unroll
        for (int ks = 0; ks < 4; ++ks)
            #pragma unroll
            for (int rt = 0; rt < 2; ++rt) {
                const float* p = xb + rt * 16 * Cc + ks * 32;
                xv[ks][rt][0] = *(const f32x4v*)p;
                xv[ks][rt][1] = *(const f32x4v*)(p + 4);
            }
        __builtin_amdgcn_sched_barrier(0);   // pin load issue here
    };

    auto compute_tile = [&](f32x4v (&xv)[4][2][2], int tile) {
        f32x4v acc[2][6];
        #pragma unroll
        for (int i = 0; i < 2; ++i)
            #pragma unroll
            for (int j = 0; j < 6; ++j)
                acc[i][j] = (f32x4v){0.f, 0.f, 0.f, 0.f};

        #pragma unroll
        for (int ks = 0; ks < 4; ++ks) {
            half8 wfrag[6];
            #pragma unroll
            for (int nt = 0; nt < 6; ++nt)
                wfrag[nt] = *(const half8*)&Wt[nt * 16 + c][ks * 32 + g * 8];
            #pragma unroll
            for (int rt = 0; rt < 2; ++rt) {
                f32x4v lo = xv[ks][rt][0], hi = xv[ks][rt][1];
                H8 bu;
                bu.p[0] = __builtin_amdgcn_cvt_pkrtz(lo[0], lo[1]);
                bu.p[1] = __builtin_amdgcn_cvt_pkrtz(lo[2], lo[3]);
                bu.p[2] = __builtin_amdgcn_cvt_pkrtz(hi[0], hi[1]);
                bu.p[3] = __builtin_amdgcn_cvt_pkrtz(hi[2], hi[3]);
                #pragma unroll
                for (int nt = 0; nt < 6; ++nt)
                    acc[rt][nt] = __builtin_amdgcn_mfma_f32_16x16x32_f16(wfrag[nt], bu.h, acc[rt][nt], 0, 0, 0);
            }
        }

        // anchors: tiles never cross an image (200 tiles/img) or a grid row (80|16)
        const int pos0 = (tile % 200) * 32;            // wave-uniform
        #pragma unroll
        for (int rt = 0; rt < 2; ++rt) {
            const int prow = pos0 + rt * 16;           // uniform
            const int yp   = prow / Ww;                // uniform
            const int xq0  = prow - yp * Ww;           // uniform
            const float ax = ((float)(xq0 + c) + 0.5f) * sf;
            const float ay = ((float)yp + 0.5f) * sf;

            float dfl[4];
            #pragma unroll
            for (int t = 0; t < 4; ++t) {
                f32x4v v = acc[rt][t] + bl[t];
                float e0 = __builtin_amdgcn_exp2f(LOG2E * v[0]);
                float e1 = __builtin_amdgcn_exp2f(LOG2E * v[1]);
                float e2 = __builtin_amdgcn_exp2f(LOG2E * v[2]);
                float e3 = __builtin_amdgcn_exp2f(LOG2E * v[3]);
                float s  = e0 + e1 + e2 + e3;
                float ws = e1 + 2.f * e2 + 3.f * e3 + (float)(4 * g) * s;
                s  += __shfl_xor(s, 16, 64);
                s  += __shfl_xor(s, 32, 64);
                ws += __shfl_xor(ws, 16, 64);
                ws += __shfl_xor(ws, 32, 64);
                dfl[t] = ws * __builtin_amdgcn_rcpf(s);
            }
            const float w2 = dfl[2] - dfl[0], w3 = dfl[3] - dfl[1];

            // stage this row's outputs into per-wave LDS scratch
            float* row = sc[wave][rt * 16 + c];
            f32x4v vA = acc[rt][4] + bl[4];
            f32x4v clsA = { sigm(vA[0]), sigm(vA[1]), sigm(vA[2]), sigm(vA[3]) };
            *(f32x4v*)(row + 4 + 4 * g) = clsA;
            if (g == 0) {
                f32x4v box = { ax + 0.5f * w2, ay + 0.5f * w3, w2, w3 };
                *(f32x4v*)row = box;
                f32x4v vB = acc[rt][5] + bl[5];
                f32x4v clsB = { sigm(vB[0]), sigm(vB[1]), sigm(vB[2]), sigm(vB[3]) };
                *(f32x4v*)(row + 20) = clsB;
            }
        }

        // dense write-out: 32 rows x 24 floats = 192 float4s, 3 per lane
        const float* s0 = &sc[wave][0][0];
        float* orow = out + (size_t)tile * 32 * 24;
        #pragma unroll
        for (int i = 0; i < 3; ++i) {
            f32x4v v = *(const f32x4v*)(s0 + (lane + 64 * i) * 4);
            *(f32x4v*)(orow + (lane + 64 * i) * 4) = v;
        }
    };

    // ---- pipelined schedule: 16 loads always in flight ----
    load_tile(xvA, t0);
    load_tile(xvB, t1);
    compute_tile(xvA, t0);
    load_tile(xvA, t2);
    compute_tile(xvB, t1);
    if (has4) load_tile(xvB, t3);
    compute_tile(xvA, t2);
    if (has4) compute_tile(xvB, t3);
}

extern "C" void kernel_launch(void* const* d_in, const int* in_sizes, int n_in,
                              void* d_out, int out_size, void* d_ws, size_t ws_size,
                              hipStream_t stream) {
    const float* x      = (const float*)d_in[0];
    const float* w_box  = (const float*)d_in[1];
    const float* b_box  = (const float*)d_in[2];
    const float* w_cls  = (const float*)d_in[3];
    const float* b_cls  = (const float*)d_in[4];
    const int*   stride_p = (const int*)d_in[5];
    float* out = (float*)d_out;

    dim3 grid(512), block(256);
    hipLaunchKernelGGL(head_kernel, grid, block, 0, stream,
                       x, w_box, b_box, w_cls, b_cls, stride_p, out);
}

// Round 10
// 29.016 us; speedup vs baseline: 1.2382x; 1.1002x over previous
//
#include <hip/hip_runtime.h>

// Head: fused GEMM (M=204800, K=128, N=84->96 padded) + DFL softmax + box decode + sigmoid.
// R10 = R9 + shfl-free softmax via channel-permuted weights:
//   Wt row (t*16 + 4f + r) holds box channel f*16 + (4t+r)  -> lane (c,g) owns ALL
//   16 bins of DFL distribution g for its row; softmax fully lane-local (0 shfls).
//   Raw dfl_g goes through the LDS store-transpose; box decode happens in the
//   dense writeout pass (field==0 fixup with per-lane anchors).

typedef _Float16 half8 __attribute__((ext_vector_type(8)));
typedef __fp16  fp16x2 __attribute__((ext_vector_type(2)));
typedef float f32x4v __attribute__((ext_vector_type(4)));

constexpr int Cc = 128;
constexpr int NPAD = 96;             // 6 N-tiles of 16: 64 box + 20 cls + 12 pad
constexpr int WT_STRIDE = 136;       // f16 elems; 272B row -> 2-way bank alias (free)
constexpr int NTILES = 6400;         // 32-row tiles (200 tiles per image, exact)
constexpr int NWAVES = 2048;         // 512 blocks * 4 waves
constexpr float LOG2E = 1.44269504088896f;

union H8 { half8 h; fp16x2 p[4]; };

__device__ __forceinline__ float sigm(float v) {
    return __builtin_amdgcn_rcpf(1.f + __builtin_amdgcn_exp2f(-LOG2E * v));
}

__global__ __launch_bounds__(256, 2)
void head_kernel(const float* __restrict__ x,
                 const float* __restrict__ w_box,
                 const float* __restrict__ b_box,
                 const float* __restrict__ w_cls,
                 const float* __restrict__ b_cls,
                 const int*   __restrict__ stride_p,
                 float* __restrict__ out)
{
    __shared__ __align__(16) _Float16 Wt[NPAD][WT_STRIDE]; // Wt[row][k], permuted box rows
    __shared__ __align__(16) float bias_s[NPAD];           // same permuted order
    __shared__ __align__(16) float sc[4][32][24];          // per-wave store-transpose scratch

    const int tid  = threadIdx.x;
    const int wave = tid >> 6;
    const int lane = tid & 63;
    const int c    = lane & 15;     // A row-in-tile sel / B spatial-row / D col
    const int g    = lane >> 4;     // quarter-group; D row = 4g + reg; g = DFL distribution

    // ---- stage Wt (box rows PERMUTED: row t*16+4f+r <- ch f*16+4t+r) ----
    for (int i = tid; i < 128 * 16; i += 256) {
        int k   = i >> 4;
        int ch0 = (i & 15) << 2;               // multiple of 4
        int f   = ch0 >> 4;
        int b0  = ch0 & 15;                    // bin base (multiple of 4)
        int R0  = (b0 >> 2) * 16 + (f << 2);   // t*16 + 4f
        f32x4v v = *(const f32x4v*)&w_box[k * 64 + ch0];
        Wt[R0 + 0][k] = (_Float16)v[0];
        Wt[R0 + 1][k] = (_Float16)v[1];
        Wt[R0 + 2][k] = (_Float16)v[2];
        Wt[R0 + 3][k] = (_Float16)v[3];
    }
    for (int i = tid; i < 128 * 5; i += 256) {   // cls rows 64..83 direct
        int k  = i / 5;
        int c4 = (i - k * 5) << 2;
        f32x4v v = *(const f32x4v*)&w_cls[k * 20 + c4];
        Wt[64 + c4 + 0][k] = (_Float16)v[0];
        Wt[64 + c4 + 1][k] = (_Float16)v[1];
        Wt[64 + c4 + 2][k] = (_Float16)v[2];
        Wt[64 + c4 + 3][k] = (_Float16)v[3];
    }
    for (int i = tid; i < 12 * 128; i += 256) {  // zero pad rows 84..95
        int ch = 84 + (i >> 7);
        int k  = i & 127;
        Wt[ch][k] = (_Float16)0.f;
    }
    if (tid < 64) {                              // box bias, permuted
        int f = tid >> 4, b = tid & 15;
        bias_s[(b >> 2) * 16 + (f << 2) + (b & 3)] = b_box[tid];
    } else if (tid < 96) {
        bias_s[tid] = (tid < 84) ? b_cls[tid - 64] : 0.f;
    }
    __syncthreads();

    const float sf = (float)stride_p[0];
    f32x4v bl[6];
    #pragma unroll
    for (int nt = 0; nt < 6; ++nt)
        bl[nt] = *(const f32x4v*)&bias_s[nt * 16 + g * 4];

    const int wid = blockIdx.x * 4 + wave;   // 0..2047
    const int t0 = wid, t1 = wid + NWAVES, t2 = wid + 2 * NWAVES;
    const bool has4 = (wid & 7) == 0;        // one 4th-tile wave per CU
    const int t3 = 3 * NWAVES + (wid >> 3);  // [6144, 6400)

    f32x4v xvA[4][2][2], xvB[4][2][2];

    auto load_tile = [&](f32x4v (&xv)[4][2][2], int tile) {
        const float* xb = x + (size_t)(tile * 32 + c) * Cc + g * 8;
        #pragma unroll
        for (int ks = 0; ks < 4; ++ks)
            #pragma unroll
            for (int rt = 0; rt < 2; ++rt) {
                const float* p = xb + rt * 16 * Cc + ks * 32;
                xv[ks][rt][0] = *(const f32x4v*)p;
                xv[ks][rt][1] = *(const f32x4v*)(p + 4);
            }
        __builtin_amdgcn_sched_barrier(0);   // pin load issue here
    };

    auto compute_tile = [&](f32x4v (&xv)[4][2][2], int tile) {
        f32x4v acc[2][6];
        #pragma unroll
        for (int i = 0; i < 2; ++i)
            #pragma unroll
            for (int j = 0; j < 6; ++j)
                acc[i][j] = (f32x4v){0.f, 0.f, 0.f, 0.f};

        #pragma unroll
        for (int ks = 0; ks < 4; ++ks) {
            half8 wfrag[6];
            #pragma unroll
            for (int nt = 0; nt < 6; ++nt)
                wfrag[nt] = *(const half8*)&Wt[nt * 16 + c][ks * 32 + g * 8];
            #pragma unroll
            for (int rt = 0; rt < 2; ++rt) {
                f32x4v lo = xv[ks][rt][0], hi = xv[ks][rt][1];
                H8 bu;
                bu.p[0] = __builtin_amdgcn_cvt_pkrtz(lo[0], lo[1]);
                bu.p[1] = __builtin_amdgcn_cvt_pkrtz(lo[2], lo[3]);
                bu.p[2] = __builtin_amdgcn_cvt_pkrtz(hi[0], hi[1]);
                bu.p[3] = __builtin_amdgcn_cvt_pkrtz(hi[2], hi[3]);
                #pragma unroll
                for (int nt = 0; nt < 6; ++nt)
                    acc[rt][nt] = __builtin_amdgcn_mfma_f32_16x16x32_f16(wfrag[nt], bu.h, acc[rt][nt], 0, 0, 0);
            }
        }

        const int pos0 = (tile % 200) * 32;            // wave-uniform
        #pragma unroll
        for (int rt = 0; rt < 2; ++rt) {
            const int row = rt * 16 + c;
            // lane-local DFL softmax over all 16 bins of distribution g
            float s = 0.f, ws = 0.f;
            #pragma unroll
            for (int t = 0; t < 4; ++t) {
                f32x4v v = acc[rt][t] + bl[t];
                float e0 = __builtin_amdgcn_exp2f(LOG2E * v[0]);
                float e1 = __builtin_amdgcn_exp2f(LOG2E * v[1]);
                float e2 = __builtin_amdgcn_exp2f(LOG2E * v[2]);
                float e3 = __builtin_amdgcn_exp2f(LOG2E * v[3]);
                s  += e0 + e1 + e2 + e3;
                ws += (float)(4 * t) * e0 + (float)(4 * t + 1) * e1
                    + (float)(4 * t + 2) * e2 + (float)(4 * t + 3) * e3;
            }
            const float dfl = ws * __builtin_amdgcn_rcpf(s);

            float* rp = sc[wave][row];
            rp[g] = dfl;                               // raw dfl_g; decoded in writeout
            f32x4v vA = acc[rt][4] + bl[4];
            f32x4v clsA = { sigm(vA[0]), sigm(vA[1]), sigm(vA[2]), sigm(vA[3]) };
            *(f32x4v*)(rp + 4 + 4 * g) = clsA;
            if (g == 0) {
                f32x4v vB = acc[rt][5] + bl[5];
                f32x4v clsB = { sigm(vB[0]), sigm(vB[1]), sigm(vB[2]), sigm(vB[3]) };
                *(f32x4v*)(rp + 20) = clsB;
            }
        }

        // dense write-out: 192 float4s, 3 per lane; field==0 gets box decode fixup
        const float* s0 = &sc[wave][0][0];
        float* orow = out + (size_t)tile * 32 * 24;
        #pragma unroll
        for (int i = 0; i < 3; ++i) {
            const unsigned j = (unsigned)lane + 64u * i;
            f32x4v v = *(const f32x4v*)(s0 + j * 4);
            const unsigned row = j / 6u;
            if (j - 6u * row == 0u) {
                const unsigned pos = (unsigned)pos0 + row;
                const unsigned yp  = pos / 80u;
                const unsigned xq  = pos - 80u * yp;
                const float ax = ((float)xq + 0.5f) * sf;
                const float ay = ((float)yp + 0.5f) * sf;
                const float w2 = v[2] - v[0], w3 = v[3] - v[1];
                v = (f32x4v){ ax + 0.5f * w2, ay + 0.5f * w3, w2, w3 };
            }
            *(f32x4v*)(orow + j * 4) = v;
        }
    };

    // ---- pipelined schedule: 16 loads always in flight ----
    load_tile(xvA, t0);
    load_tile(xvB, t1);
    compute_tile(xvA, t0);
    load_tile(xvA, t2);
    compute_tile(xvB, t1);
    if (has4) load_tile(xvB, t3);
    compute_tile(xvA, t2);
    if (has4) compute_tile(xvB, t3);
}

extern "C" void kernel_launch(void* const* d_in, const int* in_sizes, int n_in,
                              void* d_out, int out_size, void* d_ws, size_t ws_size,
                              hipStream_t stream) {
    const float* x      = (const float*)d_in[0];
    const float* w_box  = (const float*)d_in[1];
    const float* b_box  = (const float*)d_in[2];
    const float* w_cls  = (const float*)d_in[3];
    const float* b_cls  = (const float*)d_in[4];
    const int*   stride_p = (const int*)d_in[5];
    float* out = (float*)d_out;

    dim3 grid(512), block(256);
    hipLaunchKernelGGL(head_kernel, grid, block, 0, stream,
                       x, w_box, b_box, w_cls, b_cls, stride_p, out);
}

// Round 11
// 28.466 us; speedup vs baseline: 1.2621x; 1.0193x over previous
//
#include <hip/hip_runtime.h>

// Head: fused GEMM (M=204800, K=128, N=84->96 padded) + DFL softmax + box decode + sigmoid.
// R11 = R10 + register-hoisted weight fragments (zero LDS reads in main loop):
//   - wf[4][6] half8 read ONCE per wave after the barrier (24 ds_read_b128 total,
//     was 75/wave), MFMA runs pure-register thereafter.
//   - 16-row tiles (12800) so double-buffered x + wf fit in 256 VGPRs.
//   - bias folded into accumulator INIT (acc = bias, from LDS) -- epilogue adds gone.
//   - shfl-free lane-local softmax via permuted weight rows (R10).
//   - heavy 7th tile rotated across SIMDs: wave == blockIdx&3.

typedef _Float16 half8 __attribute__((ext_vector_type(8)));
typedef __fp16  fp16x2 __attribute__((ext_vector_type(2)));
typedef float f32x4v __attribute__((ext_vector_type(4)));

constexpr int Cc = 128;
constexpr int NPAD = 96;
constexpr int WT_STRIDE = 136;       // f16 elems; 272B row -> 2-way bank alias (free)
constexpr int NWAVES = 2048;         // 512 blocks * 4 waves
constexpr float LOG2E = 1.44269504088896f;

union H8 { half8 h; fp16x2 p[4]; };

__device__ __forceinline__ float sigm(float v) {
    return __builtin_amdgcn_rcpf(1.f + __builtin_amdgcn_exp2f(-LOG2E * v));
}

__global__ __launch_bounds__(256, 2)
void head_kernel(const float* __restrict__ x,
                 const float* __restrict__ w_box,
                 const float* __restrict__ b_box,
                 const float* __restrict__ w_cls,
                 const float* __restrict__ b_cls,
                 const int*   __restrict__ stride_p,
                 float* __restrict__ out)
{
    __shared__ __align__(16) _Float16 Wt[NPAD][WT_STRIDE]; // permuted box rows
    __shared__ __align__(16) float bias_s[NPAD];           // same permuted order
    __shared__ __align__(16) float sc[4][16][24];          // per-wave store-transpose scratch

    const int tid  = threadIdx.x;
    const int wave = tid >> 6;
    const int lane = tid & 63;
    const int c    = lane & 15;     // A row-in-tile sel / B spatial-row / D col
    const int g    = lane >> 4;     // quarter-group; D row = 4g + reg; g = DFL distribution

    // ---- stage Wt (box rows PERMUTED: row t*16+4f+r <- ch f*16+4t+r) ----
    for (int i = tid; i < 128 * 16; i += 256) {
        int k   = i >> 4;
        int ch0 = (i & 15) << 2;
        int f   = ch0 >> 4;
        int b0  = ch0 & 15;
        int R0  = (b0 >> 2) * 16 + (f << 2);   // t*16 + 4f
        f32x4v v = *(const f32x4v*)&w_box[k * 64 + ch0];
        Wt[R0 + 0][k] = (_Float16)v[0];
        Wt[R0 + 1][k] = (_Float16)v[1];
        Wt[R0 + 2][k] = (_Float16)v[2];
        Wt[R0 + 3][k] = (_Float16)v[3];
    }
    for (int i = tid; i < 128 * 5; i += 256) {   // cls rows 64..83 direct
        int k  = i / 5;
        int c4 = (i - k * 5) << 2;
        f32x4v v = *(const f32x4v*)&w_cls[k * 20 + c4];
        Wt[64 + c4 + 0][k] = (_Float16)v[0];
        Wt[64 + c4 + 1][k] = (_Float16)v[1];
        Wt[64 + c4 + 2][k] = (_Float16)v[2];
        Wt[64 + c4 + 3][k] = (_Float16)v[3];
    }
    for (int i = tid; i < 12 * 128; i += 256) {  // zero pad rows 84..95
        int ch = 84 + (i >> 7);
        int k  = i & 127;
        Wt[ch][k] = (_Float16)0.f;
    }
    if (tid < 64) {                              // box bias, permuted
        int f = tid >> 4, b = tid & 15;
        bias_s[(b >> 2) * 16 + (f << 2) + (b & 3)] = b_box[tid];
    } else if (tid < 96) {
        bias_s[tid] = (tid < 84) ? b_cls[tid - 64] : 0.f;
    }
    __syncthreads();

    // ---- hoist weight fragments into registers ONCE (24 ds_read_b128) ----
    half8 wf[4][6];
    #pragma unroll
    for (int ks = 0; ks < 4; ++ks)
        #pragma unroll
        for (int nt = 0; nt < 6; ++nt)
            wf[ks][nt] = *(const half8*)&Wt[nt * 16 + c][ks * 32 + g * 8];

    const float sf = (float)stride_p[0];

    const int wid = blockIdx.x * 4 + wave;       // 0..2047
    // 16-row tiles: 12800 total; 6 per wave + one extra for one wave per block
    const bool heavy = (wave == (blockIdx.x & 3));   // rotates heavy wave across SIMDs
    const int t6 = 6 * NWAVES + blockIdx.x;          // [12288, 12800)

    f32x4v xvA[4][2], xvB[4][2];

    auto load_tile = [&](f32x4v (&xv)[4][2], int tile) {
        const float* xb = x + (size_t)(tile * 16 + c) * Cc + g * 8;
        #pragma unroll
        for (int ks = 0; ks < 4; ++ks) {
            const float* p = xb + ks * 32;
            xv[ks][0] = *(const f32x4v*)p;
            xv[ks][1] = *(const f32x4v*)(p + 4);
        }
        __builtin_amdgcn_sched_barrier(0);   // pin load issue here
    };

    auto compute_tile = [&](f32x4v (&xv)[4][2], int tile) {
        // acc init = bias (folds epilogue add; lives in LDS, 6 b128 reads)
        f32x4v acc[6];
        #pragma unroll
        for (int nt = 0; nt < 6; ++nt)
            acc[nt] = *(const f32x4v*)&bias_s[nt * 16 + g * 4];

        #pragma unroll
        for (int ks = 0; ks < 4; ++ks) {
            f32x4v lo = xv[ks][0], hi = xv[ks][1];
            H8 bu;
            bu.p[0] = __builtin_amdgcn_cvt_pkrtz(lo[0], lo[1]);
            bu.p[1] = __builtin_amdgcn_cvt_pkrtz(lo[2], lo[3]);
            bu.p[2] = __builtin_amdgcn_cvt_pkrtz(hi[0], hi[1]);
            bu.p[3] = __builtin_amdgcn_cvt_pkrtz(hi[2], hi[3]);
            #pragma unroll
            for (int nt = 0; nt < 6; ++nt)
                acc[nt] = __builtin_amdgcn_mfma_f32_16x16x32_f16(wf[ks][nt], bu.h, acc[nt], 0, 0, 0);
        }

        const int pos0 = (tile % 400) * 16;        // wave-uniform; never crosses y-row (80=5*16)

        // lane-local DFL softmax over all 16 bins of distribution g (bias already in acc)
        float s = 0.f, ws = 0.f;
        #pragma unroll
        for (int t = 0; t < 4; ++t) {
            f32x4v v = acc[t];
            float e0 = __builtin_amdgcn_exp2f(LOG2E * v[0]);
            float e1 = __builtin_amdgcn_exp2f(LOG2E * v[1]);
            float e2 = __builtin_amdgcn_exp2f(LOG2E * v[2]);
            float e3 = __builtin_amdgcn_exp2f(LOG2E * v[3]);
            s  += e0 + e1 + e2 + e3;
            ws += (float)(4 * t) * e0 + (float)(4 * t + 1) * e1
                + (float)(4 * t + 2) * e2 + (float)(4 * t + 3) * e3;
        }
        const float dfl = ws * __builtin_amdgcn_rcpf(s);

        float* rp = sc[wave][c];
        rp[g] = dfl;                               // raw dfl_g; decoded in writeout
        f32x4v clsA = { sigm(acc[4][0]), sigm(acc[4][1]), sigm(acc[4][2]), sigm(acc[4][3]) };
        *(f32x4v*)(rp + 4 + 4 * g) = clsA;
        if (g == 0) {
            f32x4v clsB = { sigm(acc[5][0]), sigm(acc[5][1]), sigm(acc[5][2]), sigm(acc[5][3]) };
            *(f32x4v*)(rp + 20) = clsB;
        }

        // dense write-out: 16 rows x 24 floats = 96 float4s; field==0 gets box decode
        const float* s0 = &sc[wave][0][0];
        float* orow = out + (size_t)tile * (16 * 24);
        #pragma unroll
        for (int i = 0; i < 2; ++i) {
            const int j = lane + 64 * i;
            if (j < 96) {
                f32x4v v = *(const f32x4v*)(s0 + j * 4);
                const int row = j / 6;
                if (j - 6 * row == 0) {
                    const int pos = pos0 + row;
                    const int yp  = pos / 80;
                    const int xq  = pos - 80 * yp;
                    const float ax = ((float)xq + 0.5f) * sf;
                    const float ay = ((float)yp + 0.5f) * sf;
                    const float w2 = v[2] - v[0], w3 = v[3] - v[1];
                    v = (f32x4v){ ax + 0.5f * w2, ay + 0.5f * w3, w2, w3 };
                }
                *(f32x4v*)(orow + j * 4) = v;
            }
        }
    };

    const int t0 = wid,              t1 = wid + NWAVES;
    const int t2 = wid + 2 * NWAVES, t3 = wid + 3 * NWAVES;
    const int t4 = wid + 4 * NWAVES, t5 = wid + 5 * NWAVES;

    // ---- pipelined: next tile's 8 loads in flight during each compute ----
    load_tile(xvA, t0);
    load_tile(xvB, t1);
    compute_tile(xvA, t0);  load_tile(xvA, t2);
    compute_tile(xvB, t1);  load_tile(xvB, t3);
    compute_tile(xvA, t2);  load_tile(xvA, t4);
    compute_tile(xvB, t3);  load_tile(xvB, t5);
    compute_tile(xvA, t4);  if (heavy) load_tile(xvA, t6);
    compute_tile(xvB, t5);
    if (heavy) compute_tile(xvA, t6);
}

extern "C" void kernel_launch(void* const* d_in, const int* in_sizes, int n_in,
                              void* d_out, int out_size, void* d_ws, size_t ws_size,
                              hipStream_t stream) {
    const float* x      = (const float*)d_in[0];
    const float* w_box  = (const float*)d_in[1];
    const float* b_box  = (const float*)d_in[2];
    const float* w_cls  = (const float*)d_in[3];
    const float* b_cls  = (const float*)d_in[4];
    const int*   stride_p = (const int*)d_in[5];
    float* out = (float*)d_out;

    dim3 grid(512), block(256);
    hipLaunchKernelGGL(head_kernel, grid, block, 0, stream,
                       x, w_box, b_box, w_cls, b_cls, stride_p, out);
}